// Round 6
// baseline (380459.058 us; speedup 1.0000x reference)
//
#include <hip/hip_runtime.h>

// ---------------------------------------------------------------------------
// TacotronDecoder on MI355X — persistent kernel, weights preloaded into LDS.
// Grid = 512 blocks x 256 thr, __launch_bounds__(256,2) => 2 blocks/CU
// guaranteed co-resident (VGPR<=256, 56KB LDS -> 112KB/CU <= 160KB).
//   X blocks (0-255):  LDS = dWih/dWhh rows for u-pair (48KB).
//       p2: dLSTM gates (ah|dh part). p1: dLSTM finish (ctx part) + conv/pn2.
//   Y blocks (256-511): LDS = aWih/aWhh rows for u-pair (40KB).
//       p2: energies+softmax+ctx (64) | mel/gate(t-1) | pn1/pn3. p1: aLSTM(t+1).
// Manual grid barrier: atomicAdd arrival + relaxed agent-scope LOAD polling
// (R5's RMW polling congested the atomic path). Fences as in R5 (validated).
// LDS weights are immune to the barrier fence's L2 invalidation -> the
// 43MB/step weight re-fetch measured in R5 disappears.
// ---------------------------------------------------------------------------

#define DEV_INLINE __device__ __forceinline__

constexpr int TB = 800;
constexpr unsigned NBLK = 512;

// ws float offsets (same validated layout as R5)
constexpr size_t PMT_O  = 0;          // [64][128][256]
constexpr size_t GDT_O  = 2097152;    // [2048][64]
constexpr size_t WQT_O  = 2228224;    // [512][128]
constexpr size_t LOCF_O = 2293760;    // [64][256][32]
constexpr size_t Y1_O   = 2818048;    // [256][64]
constexpr size_t Y2_O   = 2834432;    // [256][64]
constexpr size_t XR_O   = 2850816;    // [2][256][64]
constexpr size_t AH_O   = 2883584;    // [2][512][64]
constexpr size_t AC_O   = 2949120;
constexpr size_t DH_O   = 3014656;
constexpr size_t DC_O   = 3080192;
constexpr size_t CTX_O  = 3145728;
constexpr size_t AW_O   = 3211264;    // [2][64][256]
constexpr size_t AWS_O  = 3244032;    // [2][64][256]
constexpr size_t BAR_O  = 3276800;    // barrier counter (+pad)
constexpr size_t ZERO_N = 983296;     // zero span [LOCF_O, 3277056)

// out float offsets
constexpr size_t MEL_O  = 0;          // (B,T,80)
constexpr size_t GATE_O = 4096000;    // (B,T)
constexpr size_t ALG_O  = 4147200;    // (B,T,L)

DEV_INLINE float sigf(float x)     { return 1.0f / (1.0f + __expf(-x)); }
DEV_INLINE float tanhfast(float x) { float e = __expf(2.0f * x); return 1.0f - 2.0f / (e + 1.0f); }

struct Params {
  const float* enc; const int* len; const float* mels;
  const float* Wp1; const float* Wp2; const float* Wp3;
  const float* aWih; const float* aWhh; const float* abih; const float* abhh;
  const float* dWih; const float* dWhh; const float* dbih; const float* dbhh;
  const float* Wconv; const float* Wloc; const float* v;
  const float* Wout; const float* bout; const float* Wgate; const float* bgate;
  float* ws; float* out;
};

// manual grid barrier: RMW arrival, LOAD polling (no RMW congestion).
DEV_INLINE void gbar(unsigned* cnt, unsigned target)
{
  __syncthreads();
  __threadfence();                      // release (R5-validated semantics)
  if (threadIdx.x == 0) {
    atomicAdd(cnt, 1u);
    while (__hip_atomic_load(cnt, __ATOMIC_RELAXED, __HIP_MEMORY_SCOPE_AGENT) < target)
      __builtin_amdgcn_s_sleep(2);
  }
  __syncthreads();
  __threadfence();                      // acquire
}

// GEMM segment with LDS weights: wlds is [Kglobal][NO] floats; lane=batch.
template<int NO>
DEV_INLINE void gsegL(float* __restrict__ acc,
                      const float* __restrict__ inT,
                      const float* __restrict__ wlds,
                      const int segk0, const int seglen,
                      const int ks, const int ke, const int lane)
{
  const int a0 = ks > segk0 ? ks : segk0;
  const int a1 = (ke < segk0 + seglen) ? ke : (segk0 + seglen);
  if (a0 >= a1) return;
  const float* __restrict__ ip = inT + (size_t)(a0 - segk0) * 64 + lane;
  const float* __restrict__ wp = wlds + (size_t)a0 * NO;
  const int n = a1 - a0;
  for (int k = 0; k < n; k += 2) {
    const float x0 = ip[(k + 0) * 64];
    const float x1 = ip[(k + 1) * 64];
#pragma unroll
    for (int j = 0; j < NO; ++j)
      acc[j] += x0 * wp[(k + 0) * NO + j] + x1 * wp[(k + 1) * NO + j];
  }
}

// global-weight segment (for small streams: mel/gate/prenet)
template<int NO>
DEV_INLINE void gseg(float* __restrict__ acc,
                     const float* __restrict__ inT,
                     const float* __restrict__ W, const int ldw, const int wcol0,
                     const int* __restrict__ rows, const int segk0, const int seglen,
                     const int ks, const int ke, const int lane)
{
  const int a0 = ks > segk0 ? ks : segk0;
  const int a1 = (ke < segk0 + seglen) ? ke : (segk0 + seglen);
  if (a0 >= a1) return;
  const float* __restrict__ ip = inT + (size_t)(a0 - segk0) * 64 + lane;
  const int n = a1 - a0;
  const float* wp[NO];
#pragma unroll
  for (int j = 0; j < NO; ++j)
    wp[j] = W + (size_t)rows[j] * ldw + (wcol0 + (a0 - segk0));
  for (int k = 0; k < n; k += 4) {
    const float x0 = ip[(k + 0) * 64];
    const float x1 = ip[(k + 1) * 64];
    const float x2 = ip[(k + 2) * 64];
    const float x3 = ip[(k + 3) * 64];
#pragma unroll
    for (int j = 0; j < NO; ++j)
      acc[j] += x0 * wp[j][k] + x1 * wp[j][k + 1] + x2 * wp[j][k + 2] + x3 * wp[j][k + 3];
  }
}

// ---------------------------------------------------------------------------
__global__ __launch_bounds__(256) void init_kernel(const float* __restrict__ Wq,
                                                   float* __restrict__ ws)
{
  const int i = blockIdx.x * 256 + threadIdx.x;       // 65536 threads
  {
    const int k = i >> 7, a = i & 127;                // WqT[k][a] = Wq[a][k]
    ws[WQT_O + i] = Wq[a * 512 + k];
  }
  for (size_t idx = i; idx < ZERO_N; idx += 65536)    // zero locF..states..barrier
    ws[LOCF_O + idx] = 0.0f;
}

// ---------------------------------------------------------------------------
// host-side prenet for x(0), x(1): block j handles t = j, writes ring slot j.
// ---------------------------------------------------------------------------
__global__ __launch_bounds__(256) void prenet_kernel(const float* __restrict__ mels,
                                                     const float* __restrict__ Wp1,
                                                     const float* __restrict__ Wp2,
                                                     const float* __restrict__ Wp3,
                                                     float* __restrict__ xb)
{
  __shared__ float smem[16384];
  const int t = blockIdx.x;
  const int tid = threadIdx.x;
  const int lane = tid & 63;
  const int wv = __builtin_amdgcn_readfirstlane(tid >> 6);

  if (t == 0) {
    for (int i = tid; i < 5200; i += 256) smem[i] = 0.0f;
  } else {
    for (int i = tid; i < 5120; i += 256) {
      const int b = i / 80, k = i - b * 80;
      smem[k * 65 + b] = mels[((size_t)b * TB + (t - 1)) * 80 + k];
    }
  }
  __syncthreads();

  float va[8][8];
#pragma unroll
  for (int g = 0; g < 8; ++g) {                    // L1: K=80
    const int u0 = wv * 64 + g * 8;
    float acc[8] = {};
    for (int k = 0; k < 80; ++k) {
      const float x = smem[k * 65 + lane];
#pragma unroll
      for (int j = 0; j < 8; ++j) acc[j] += x * Wp1[(u0 + j) * 80 + k];
    }
#pragma unroll
    for (int j = 0; j < 8; ++j) va[g][j] = fmaxf(acc[j], 0.0f);
  }
  __syncthreads();
#pragma unroll
  for (int g = 0; g < 8; ++g)
#pragma unroll
    for (int j = 0; j < 8; ++j) smem[(wv * 64 + g * 8 + j) * 64 + lane] = va[g][j];
  __syncthreads();

#pragma unroll
  for (int g = 0; g < 8; ++g) {                    // L2: K=256
    const int u0 = wv * 64 + g * 8;
    float acc[8] = {};
    for (int k = 0; k < 256; ++k) {
      const float x = smem[k * 64 + lane];
#pragma unroll
      for (int j = 0; j < 8; ++j) acc[j] += x * Wp2[(u0 + j) * 256 + k];
    }
#pragma unroll
    for (int j = 0; j < 8; ++j) va[g][j] = fmaxf(acc[j], 0.0f);
  }
  __syncthreads();
#pragma unroll
  for (int g = 0; g < 8; ++g)
#pragma unroll
    for (int j = 0; j < 8; ++j) smem[(wv * 64 + g * 8 + j) * 64 + lane] = va[g][j];
  __syncthreads();

#pragma unroll
  for (int g = 0; g < 8; ++g) {                    // L3: K=256 -> ring slot
    const int u0 = wv * 64 + g * 8;
    float acc[8] = {};
    for (int k = 0; k < 256; ++k) {
      const float x = smem[k * 64 + lane];
#pragma unroll
      for (int j = 0; j < 8; ++j) acc[j] += x * Wp3[(u0 + j) * 256 + k];
    }
#pragma unroll
    for (int j = 0; j < 8; ++j)
      xb[((size_t)t * 256 + (u0 + j)) * 64 + lane] = fmaxf(acc[j], 0.0f);
  }
}

// ---------------------------------------------------------------------------
// processed_memory: pmT[b][a][l] = sum_k enc[b,l,k]*Wm[a,k]. 256 blocks.
// ---------------------------------------------------------------------------
__global__ __launch_bounds__(256) void pm_kernel(const float* __restrict__ enc,
                                                 const float* __restrict__ Wm,
                                                 float* __restrict__ pmT)
{
  __shared__ float encL[64 * 129];
  const int b = blockIdx.x >> 2;
  const int l0 = (blockIdx.x & 3) * 64;
  const int tid = threadIdx.x;
  const int lane = tid & 63;
  const int wv = __builtin_amdgcn_readfirstlane(tid >> 6);

  float acc[4][8];
#pragma unroll
  for (int ai = 0; ai < 4; ++ai)
#pragma unroll
    for (int j = 0; j < 8; ++j) acc[ai][j] = 0.0f;

  for (int kc = 0; kc < 4; ++kc) {
    __syncthreads();
    for (int i = tid; i < 64 * 128; i += 256) {
      const int l = i >> 7, k = i & 127;
      encL[l * 129 + k] = enc[((size_t)b * 256 + l0 + l) * 512 + kc * 128 + k];
    }
    __syncthreads();
#pragma unroll
    for (int ai = 0; ai < 4; ++ai) {
      const int agrp = (ai * 4 + wv) * 8;
      for (int k = 0; k < 128; ++k) {
        const float x = encL[lane * 129 + k];
#pragma unroll
        for (int j = 0; j < 8; ++j)
          acc[ai][j] += x * Wm[(size_t)(agrp + j) * 512 + kc * 128 + k];
      }
    }
  }
#pragma unroll
  for (int ai = 0; ai < 4; ++ai) {
    const int agrp = (ai * 4 + wv) * 8;
#pragma unroll
    for (int j = 0; j < 8; ++j)
      pmT[((size_t)b * 128 + agrp + j) * 256 + l0 + lane] = acc[ai][j];
  }
}

// ------------------------- persistent-kernel roles -------------------------
// rows[j] = u0 + (j>>2) + 512*(j&3)  (j&3 = gate, j>>2 = u offset)

// aLSTM for u-pair from LDS weights wAL[[0,1280)][8]
DEV_INLINE void f_alstm2(int u0, int tid, int lane, int wv,
                         const float* __restrict__ xt, const float* __restrict__ ctx,
                         const float* __restrict__ ah_i, const float* __restrict__ ac_i,
                         float* __restrict__ ah_o, float* __restrict__ ac_o,
                         const float* __restrict__ wAL, const Params& p, float* sm)
{
  float acc[8] = {};
  const int ks = wv * 320, ke = ks + 320;           // K = 256+512+512
  gsegL<8>(acc, xt,   wAL, 0,   256, ks, ke, lane);
  gsegL<8>(acc, ctx,  wAL, 256, 512, ks, ke, lane);
  gsegL<8>(acc, ah_i, wAL, 768, 512, ks, ke, lane);
#pragma unroll
  for (int j = 0; j < 8; ++j) sm[(wv * 8 + j) * 64 + lane] = acc[j];
  __syncthreads();
  if (tid < 128) {
    const int m = tid & 63, uq = tid >> 6;
    const int u = u0 + uq;
    float g[4];
#pragma unroll
    for (int q = 0; q < 4; ++q) {
      const int j = uq * 4 + q;
      g[q] = sm[j * 64 + m] + sm[(8 + j) * 64 + m] + sm[(16 + j) * 64 + m] + sm[(24 + j) * 64 + m]
           + p.abih[u + 512 * q] + p.abhh[u + 512 * q];
    }
    const float co = ac_i[u * 64 + m], ho = ah_i[u * 64 + m];
    const float c2 = sigf(g[1]) * co + sigf(g[0]) * tanhfast(g[2]);
    const float h2 = sigf(g[3]) * tanhfast(c2);
    ah_o[u * 64 + m] = 0.1f * ho + 0.9f * h2;
    ac_o[u * 64 + m] = 0.1f * co + 0.9f * c2;
  }
  __syncthreads();
}

// dLSTM partial gates for u-pair from LDS wDG[[0,1024)][8]
DEV_INLINE void f_dgates2(int u0, int tid, int lane, int wv,
                          const float* __restrict__ ah, const float* __restrict__ dh,
                          float* __restrict__ gdT, const float* __restrict__ wDG,
                          const Params& p, float* sm)
{
  float acc[8] = {};
  const int ks = wv * 256, ke = ks + 256;           // K = 1024 (ah | dh)
  gsegL<8>(acc, ah, wDG, 0,   512, ks, ke, lane);
  gsegL<8>(acc, dh, wDG, 512, 512, ks, ke, lane);
#pragma unroll
  for (int j = 0; j < 8; ++j) sm[(wv * 8 + j) * 64 + lane] = acc[j];
  __syncthreads();
  if (tid < 128) {
    const int m = tid & 63, uq = tid >> 6;
    const int u = u0 + uq;
#pragma unroll
    for (int q = 0; q < 4; ++q) {
      const int j = uq * 4 + q;
      gdT[(size_t)(u + 512 * q) * 64 + m] =
          sm[j * 64 + m] + sm[(8 + j) * 64 + m] + sm[(16 + j) * 64 + m] + sm[(24 + j) * 64 + m]
        + p.dbih[u + 512 * q] + p.dbhh[u + 512 * q];
    }
  }
  __syncthreads();
}

// dLSTM finish for u-pair from LDS wDF[[0,512)][8]
DEV_INLINE void f_dfin2(int u0, int tid, int lane, int wv,
                        const float* __restrict__ ctx, const float* __restrict__ gdT,
                        const float* __restrict__ dh_p, const float* __restrict__ dc_p,
                        float* __restrict__ dh_o, float* __restrict__ dc_o,
                        const float* __restrict__ wDF, const Params& p, float* sm)
{
  float acc[8] = {};
  const int ks = wv * 128, ke = ks + 128;           // K = 512 (ctx)
  gsegL<8>(acc, ctx, wDF, 0, 512, ks, ke, lane);
#pragma unroll
  for (int j = 0; j < 8; ++j) sm[(wv * 8 + j) * 64 + lane] = acc[j];
  __syncthreads();
  if (tid < 128) {
    const int m = tid & 63, uq = tid >> 6;
    const int u = u0 + uq;
    float g[4];
#pragma unroll
    for (int q = 0; q < 4; ++q) {
      const int j = uq * 4 + q;
      g[q] = sm[j * 64 + m] + sm[(8 + j) * 64 + m] + sm[(16 + j) * 64 + m] + sm[(24 + j) * 64 + m]
           + gdT[(size_t)(u + 512 * q) * 64 + m];
    }
    const float co = dc_p[u * 64 + m], ho = dh_p[u * 64 + m];
    const float c2 = sigf(g[1]) * co + sigf(g[0]) * tanhfast(g[2]);
    const float h2 = sigf(g[3]) * tanhfast(c2);
    dh_o[u * 64 + m] = 0.1f * ho + 0.9f * h2;
    dc_o[u * 64 + m] = 0.1f * co + 0.9f * c2;
  }
  __syncthreads();
}

DEV_INLINE void f_mel(int c0, int tid, int lane, int wv, int tm1,
                      const float* __restrict__ dh, const float* __restrict__ ctx,
                      const Params& p, float* sm)
{
  int rows[4] = {c0, c0 + 1, c0 + 2, c0 + 3};
  float acc[4] = {};
  const int ks = wv * 256, ke = ks + 256;           // K = 1024
  gseg<4>(acc, dh,  p.Wout, 1024, 0,   rows, 0,   512, ks, ke, lane);
  gseg<4>(acc, ctx, p.Wout, 1024, 512, rows, 512, 512, ks, ke, lane);
#pragma unroll
  for (int j = 0; j < 4; ++j) sm[(wv * 4 + j) * 64 + lane] = acc[j];
  __syncthreads();
  {
    const int m = tid & 63, c = tid >> 6;
    const float val = sm[c * 64 + m] + sm[(4 + c) * 64 + m] + sm[(8 + c) * 64 + m] + sm[(12 + c) * 64 + m]
                    + p.bout[c0 + c];
    p.out[MEL_O + ((size_t)m * TB + tm1) * 80 + c0 + c] = val;
  }
  __syncthreads();
}

DEV_INLINE void f_gate(int tid, int lane, int wv, int tm1,
                       const float* __restrict__ dh, const float* __restrict__ ctx,
                       const Params& p, float* sm)
{
  float acc[1] = {};
  int rows1[1] = {0};
  const int ks = wv * 256, ke = ks + 256;
  gseg<1>(acc, dh,  p.Wgate, 1024, 0,   rows1, 0,   512, ks, ke, lane);
  gseg<1>(acc, ctx, p.Wgate, 1024, 512, rows1, 512, 512, ks, ke, lane);
  sm[wv * 64 + lane] = acc[0];
  __syncthreads();
  if (tid < 64) {
    const float val = sm[tid] + sm[64 + tid] + sm[128 + tid] + sm[192 + tid] + p.bgate[0];
    p.out[GATE_O + (size_t)tid * TB + tm1] = val;
  }
  __syncthreads();
}

DEV_INLINE void f_conv(int b, int tid,
                       const float* __restrict__ aw, const float* __restrict__ aws,
                       float* __restrict__ locF, const Params& p, float* sm)
{
  float* awL  = sm;          // 286 (+pad)
  float* awsL = sm + 290;
  if (tid < 15) { awL[tid] = 0.0f; awsL[tid] = 0.0f; awL[271 + tid] = 0.0f; awsL[271 + tid] = 0.0f; }
  awL[15 + tid]  = aw[b * 256 + tid];
  awsL[15 + tid] = aws[b * 256 + tid];
  __syncthreads();
  float awv[31], awsv[31];
#pragma unroll
  for (int k = 0; k < 31; ++k) { awv[k] = awL[tid + k]; awsv[k] = awsL[tid + k]; }
  float* dst = locF + ((size_t)b * 256 + tid) * 32;
  for (int f = 0; f < 32; ++f) {
    const float* wc = p.Wconv + f * 62;
    float lf = 0.0f;
#pragma unroll
    for (int k = 0; k < 31; ++k) lf += awv[k] * wc[k] + awsv[k] * wc[31 + k];
    dst[f] = lf;
  }
  __syncthreads();
}

DEV_INLINE void f_energy(int b, int t, int tid, int lane, int wv,
                         const float* __restrict__ ah, const float* __restrict__ aws_p,
                         float* __restrict__ ctx_o, float* __restrict__ aw_o,
                         float* __restrict__ aws_o,
                         const float* __restrict__ pmT, const float* __restrict__ wqT,
                         const float* __restrict__ locF, const Params& p, float* sm)
{
  float* ahL = sm;          // 512
  float* qpL = sm + 512;    // 256
  float* qL  = sm + 768;    // 128
  float* red = sm + 896;    // 16
  float* wL  = sm + 912;    // 256
  ahL[tid]       = ah[(size_t)tid * 64 + b];
  ahL[tid + 256] = ah[(size_t)(tid + 256) * 64 + b];
  __syncthreads();
  {
    const int a = tid & 127, h = tid >> 7;
    float qp = 0.0f;
    const float* wq = wqT + (size_t)(h * 256) * 128 + a;
    const float* xv = ahL + h * 256;
    for (int k = 0; k < 256; k += 4)
      qp += wq[(k + 0) * 128] * xv[k + 0] + wq[(k + 1) * 128] * xv[k + 1]
          + wq[(k + 2) * 128] * xv[k + 2] + wq[(k + 3) * 128] * xv[k + 3];
    qpL[tid] = qp;
  }
  __syncthreads();
  if (tid < 128) qL[tid] = qpL[tid] + qpL[128 + tid];
  __syncthreads();

  float locv[32];
  {
    const float4* lf4 = (const float4*)(locF + ((size_t)b * 256 + tid) * 32);
#pragma unroll
    for (int i = 0; i < 8; ++i) {
      float4 x = lf4[i];
      locv[4*i] = x.x; locv[4*i+1] = x.y; locv[4*i+2] = x.z; locv[4*i+3] = x.w;
    }
  }
  float part = 0.0f;
  const float* pmp = pmT + (size_t)b * 32768 + tid;     // pm[b][a][l=tid]
#pragma unroll 2
  for (int a = 0; a < 128; ++a) {
    float s = qL[a] + pmp[(size_t)a * 256];
    const float* wl = p.Wloc + a * 32;
#pragma unroll
    for (int f = 0; f < 32; ++f) s += locv[f] * wl[f];
    part += p.v[a] * tanhfast(s);
  }
  if (tid >= p.len[b]) part = -1e9f;

  float mv = part;
  for (int mm = 32; mm >= 1; mm >>= 1) mv = fmaxf(mv, __shfl_xor(mv, mm, 64));
  if (lane == 0) red[wv] = mv;
  __syncthreads();
  const float mx = fmaxf(fmaxf(red[0], red[1]), fmaxf(red[2], red[3]));
  const float pex = __expf(part - mx);
  float ssum = pex;
  for (int mm = 32; mm >= 1; mm >>= 1) ssum += __shfl_xor(ssum, mm, 64);
  if (lane == 0) red[8 + wv] = ssum;
  __syncthreads();
  const float inv = 1.0f / (red[8] + red[9] + red[10] + red[11]);
  const float w = pex * inv;
  wL[tid] = w;
  aw_o[b * 256 + tid]  = w;
  aws_o[b * 256 + tid] = aws_p[b * 256 + tid] + w;
  p.out[ALG_O + ((size_t)b * TB + t) * 256 + tid] = w;
  __syncthreads();

  float c0 = 0.0f, c1 = 0.0f;
  const float* ep = p.enc + (size_t)b * 256 * 512;
  for (int l = 0; l < 256; ++l) {
    const float wv_ = wL[l];
    c0 += wv_ * ep[(size_t)l * 512 + tid];
    c1 += wv_ * ep[(size_t)l * 512 + tid + 256];
  }
  ctx_o[(size_t)tid * 64 + b]         = c0;
  ctx_o[(size_t)(tid + 256) * 64 + b] = c1;
  __syncthreads();
}

// prenet L1: 8 blocks x 32 u; reads mels[:, frame]
DEV_INLINE void f_pn1(int blkL, int frame, int lane, int wv,
                      const Params& p, float* __restrict__ y1)
{
  const int u0 = blkL * 32 + wv * 8;
  float acc[8] = {};
  const float* mp = p.mels + ((size_t)lane * TB + frame) * 80;
  for (int k = 0; k < 80; ++k) {
    const float x = mp[k];
#pragma unroll
    for (int j = 0; j < 8; ++j) acc[j] += x * p.Wp1[(u0 + j) * 80 + k];
  }
#pragma unroll
  for (int j = 0; j < 8; ++j) y1[(size_t)(u0 + j) * 64 + lane] = fmaxf(acc[j], 0.0f);
}

// prenet mid layer (L2 or L3): yin [256][64] -> yout [256][64]
DEV_INLINE void f_pnmid(int blkL, int lane, int wv,
                        const float* __restrict__ yin, const float* __restrict__ W,
                        float* __restrict__ yout)
{
  const int u0 = blkL * 32 + wv * 8;
  float acc[8] = {};
  for (int k = 0; k < 256; ++k) {
    const float x = yin[(size_t)k * 64 + lane];
#pragma unroll
    for (int j = 0; j < 8; ++j) acc[j] += x * W[(u0 + j) * 256 + k];
  }
#pragma unroll
  for (int j = 0; j < 8; ++j) yout[(size_t)(u0 + j) * 64 + lane] = fmaxf(acc[j], 0.0f);
}

// ---------------------------------------------------------------------------
__global__ __launch_bounds__(256, 2) void persist_kernel(Params p)
{
  __shared__ float lds[14336];     // 56KB
  const int tid = threadIdx.x, blk = blockIdx.x;
  const int lane = tid & 63;
  const int wv = __builtin_amdgcn_readfirstlane(tid >> 6);
  const bool isX = blk < 256;
  const int yi = blk - 256;

  float* ws   = p.ws;
  float* pmT  = ws + PMT_O;
  float* gdT  = ws + GDT_O;
  float* wqT  = ws + WQT_O;
  float* locF = ws + LOCF_O;
  float* y1   = ws + Y1_O;
  float* y2   = ws + Y2_O;
  float* xr   = ws + XR_O;
  float* AH[2]  = {ws + AH_O,  ws + AH_O  + 32768};
  float* AC[2]  = {ws + AC_O,  ws + AC_O  + 32768};
  float* DH[2]  = {ws + DH_O,  ws + DH_O  + 32768};
  float* DC[2]  = {ws + DC_O,  ws + DC_O  + 32768};
  float* CTX[2] = {ws + CTX_O, ws + CTX_O + 32768};
  float* AW[2]  = {ws + AW_O,  ws + AW_O  + 16384};
  float* AWS[2] = {ws + AWS_O, ws + AWS_O + 16384};
  unsigned* cnt = (unsigned*)(ws + BAR_O);
  unsigned nbar = 0;

  // LDS layout per role
  float* wDG = lds;            // X: [1024][8] = 8192
  float* wDF = lds + 8192;     // X: [512][8]  = 4096
  float* smX = lds + 12288;    // X scratch 2048
  float* wAL = lds;            // Y: [1280][8] = 10240
  float* smY = lds + 10240;    // Y scratch 2048
  float* sm  = isX ? smX : smY;

  // ---- weight preload (once) ----
  if (isX) {
    const int u0 = blk * 2;
    for (int j = 0; j < 8; ++j) {
      const int row = u0 + (j >> 2) + 512 * (j & 3);
      const float* dwih = p.dWih + (size_t)row * 1024;
      const float* dwhh = p.dWhh + (size_t)row * 512;
      for (int k = tid; k < 512; k += 256) {
        wDG[k * 8 + j]         = dwih[k];
        wDG[(512 + k) * 8 + j] = dwhh[k];
        wDF[k * 8 + j]         = dwih[512 + k];
      }
    }
  } else {
    const int u0 = yi * 2;
    for (int j = 0; j < 8; ++j) {
      const int row = u0 + (j >> 2) + 512 * (j & 3);
      const float* awih = p.aWih + (size_t)row * 768;
      const float* awhh = p.aWhh + (size_t)row * 512;
      for (int k = tid; k < 768; k += 256) wAL[k * 8 + j] = awih[k];
      for (int k = tid; k < 512; k += 256) wAL[(768 + k) * 8 + j] = awhh[k];
    }
  }
  __syncthreads();

  // S0: prenet L1 for x(2) (frame = mels[:,1])
  if (blk < 8) f_pn1(blk, 1, lane, wv, p, y1);
  ++nbar; gbar(cnt, nbar * NBLK);

  // S1: aLSTM(0) from zero state (Y) || pn L2(x(2)) (X 64-71). locF(0)=0.
  if (!isX) {
    f_alstm2(yi * 2, tid, lane, wv, xr, CTX[1], AH[1], AC[1], AH[0], AC[0], wAL, p, sm);
  } else if (blk >= 64 && blk < 72) {
    f_pnmid(blk - 64, lane, wv, y1, p.Wp2, y2);
  }
  ++nbar; gbar(cnt, nbar * NBLK);

  for (int t = 0; t < TB; ++t) {
    const int cur = t & 1, prv = cur ^ 1;
    // ---- p2(t) ----
    if (isX) {
      f_dgates2(blk * 2, tid, lane, wv, AH[cur], DH[prv], gdT, wDG, p, sm);
    } else if (yi < 64) {
      f_energy(yi, t, tid, lane, wv, AH[cur], AWS[prv],
               CTX[cur], AW[cur], AWS[cur], pmT, wqT, locF, p, sm);
    } else if (yi < 84) {
      if (t > 0) f_mel((yi - 64) * 4, tid, lane, wv, t - 1, DH[prv], CTX[prv], p, sm);
    } else if (yi == 84) {
      if (t > 0) f_gate(tid, lane, wv, t - 1, DH[prv], CTX[prv], p, sm);
    } else if (yi < 93) {
      if (t <= 796) f_pn1(yi - 85, t + 2, lane, wv, p, y1);            // L1 for x(t+3)
    } else if (yi < 101) {
      if (t <= 797) f_pnmid(yi - 93, lane, wv, y2, p.Wp3, xr + (size_t)cur * 16384); // L3 -> x(t+2)
    }
    ++nbar; gbar(cnt, nbar * NBLK);

    // ---- p1(t) ----
    if (isX) {
      f_dfin2(blk * 2, tid, lane, wv, CTX[cur], gdT, DH[prv], DC[prv],
              DH[cur], DC[cur], wDF, p, sm);
      if (blk < 64) {
        if (t < TB - 1) f_conv(blk, tid, AW[cur], AWS[cur], locF, p, sm);   // locF(t+1)
      } else if (blk < 72) {
        if (t <= 796) f_pnmid(blk - 64, lane, wv, y1, p.Wp2, y2);           // L2 for x(t+3)
      }
    } else {
      if (t < TB - 1)
        f_alstm2(yi * 2, tid, lane, wv, xr + (size_t)prv * 16384, CTX[cur],
                 AH[cur], AC[cur], AH[prv], AC[prv], wAL, p, sm);
    }
    ++nbar; gbar(cnt, nbar * NBLK);
  }
  // final mel/gate for t = 799 (dh,ctx in buf[1])
  if (!isX) {
    if (yi >= 64 && yi < 84)  f_mel((yi - 64) * 4, tid, lane, wv, TB - 1, DH[1], CTX[1], p, sm);
    else if (yi == 84)        f_gate(tid, lane, wv, TB - 1, DH[1], CTX[1], p, sm);
  }
}

// ---------------------------------------------------------------------------
extern "C" void kernel_launch(void* const* d_in, const int* in_sizes, int n_in,
                              void* d_out, int out_size, void* d_ws, size_t ws_size,
                              hipStream_t stream)
{
  (void)in_sizes; (void)n_in; (void)out_size; (void)ws_size;
  Params P;
  P.enc   = (const float*)d_in[0];
  P.len   = (const int*)  d_in[1];
  P.mels  = (const float*)d_in[2];
  P.Wp1   = (const float*)d_in[3];
  P.Wp2   = (const float*)d_in[4];
  P.Wp3   = (const float*)d_in[5];
  P.aWih  = (const float*)d_in[6];
  P.aWhh  = (const float*)d_in[7];
  P.abih  = (const float*)d_in[8];
  P.abhh  = (const float*)d_in[9];
  P.dWih  = (const float*)d_in[10];
  P.dWhh  = (const float*)d_in[11];
  P.dbih  = (const float*)d_in[12];
  P.dbhh  = (const float*)d_in[13];
  const float* Wq = (const float*)d_in[14];
  const float* Wm = (const float*)d_in[15];
  P.Wconv = (const float*)d_in[16];
  P.Wloc  = (const float*)d_in[17];
  P.v     = (const float*)d_in[18];
  P.Wout  = (const float*)d_in[19];
  P.bout  = (const float*)d_in[20];
  P.Wgate = (const float*)d_in[21];
  P.bgate = (const float*)d_in[22];
  P.ws  = (float*)d_ws;
  P.out = (float*)d_out;

  init_kernel<<<256, 256, 0, stream>>>(Wq, P.ws);
  pm_kernel<<<256, 256, 0, stream>>>(P.enc, Wm, P.ws + PMT_O);
  prenet_kernel<<<2, 256, 0, stream>>>(P.mels, P.Wp1, P.Wp2, P.Wp3, P.ws + XR_O);

  persist_kernel<<<NBLK, 256, 0, stream>>>(P);
}

// Round 7
// 101821.484 us; speedup vs baseline: 3.7365x; 3.7365x over previous
//
#include <hip/hip_runtime.h>

// ---------------------------------------------------------------------------
// TacotronDecoder on MI355X — persistent kernel, captain-fence coherence.
// Key changes vs R6 (380ms, per-block __threadfence = 97% of time):
//  * All cross-block global WRITES are agent-scope sc1 stores (write-through,
//    never dirty in L2) -> no L2 writeback needed anywhere.
//  * Barrier: tree arrivals (8 group counters + root, relaxed agent atomics);
//    ONE captain block per XCD (elected via HW_REG_XCC_ID) executes the agent
//    acquire fence (L2 inv). All blocks do a cheap local vL1 inv (buffer_inv sc0).
//  * Reads stay normal cached loads -> state/constant fan-out served by L2.
//  * 4 LSTM units per block (256 blocks total); gd + own h/c state in LDS.
// ---------------------------------------------------------------------------

#define DEV_INLINE __device__ __forceinline__

constexpr int TB = 800;

// ws float offsets
constexpr size_t PMT_O  = 0;          // [64][128][256]
constexpr size_t WQT_O  = 2228224;    // [512][128]
constexpr size_t LOCF_O = 2293760;    // [64][256][32]
constexpr size_t Y1_O   = 2818048;    // [256][64]
constexpr size_t Y2_O   = 2834432;    // [256][64]
constexpr size_t XR_O   = 2850816;    // [2][256][64]
constexpr size_t AH_O   = 2883584;    // [2][512][64]
constexpr size_t AC_O   = 2949120;    // (unused: ac in LDS)
constexpr size_t DH_O   = 3014656;    // [2][512][64]
constexpr size_t DC_O   = 3080192;    // (unused: dc in LDS)
constexpr size_t CTX_O  = 3145728;    // [2][512][64]
constexpr size_t AW_O   = 3211264;    // [2][64][256]
constexpr size_t AWS_O  = 3244032;    // [2][64][256]
constexpr size_t BAR_O  = 3276800;    // barrier region (8192 floats)
constexpr size_t ZERO_N = 991232;     // zero span [LOCF_O, BAR_O+8192)

// out float offsets
constexpr size_t MEL_O  = 0;          // (B,T,80)
constexpr size_t GATE_O = 4096000;    // (B,T)
constexpr size_t ALG_O  = 4147200;    // (B,T,L)

DEV_INLINE float sigf(float x)     { return 1.0f / (1.0f + __expf(-x)); }
DEV_INLINE float tanhfast(float x) { float e = __expf(2.0f * x); return 1.0f - 2.0f / (e + 1.0f); }

// agent-scope (sc1) write-through store: visible device-wide once vmcnt drains;
// never leaves a dirty line in L2 (so buffer_inv can't lose data).
DEV_INLINE void stc(float* p, float v) {
  __hip_atomic_store(p, v, __ATOMIC_RELAXED, __HIP_MEMORY_SCOPE_AGENT);
}

struct Params {
  const float* enc; const int* len; const float* mels;
  const float* Wp1; const float* Wp2; const float* Wp3;
  const float* aWih; const float* aWhh; const float* abih; const float* abhh;
  const float* dWih; const float* dWhh; const float* dbih; const float* dbhh;
  const float* Wconv; const float* Wloc; const float* v;
  const float* Wout; const float* bout; const float* Wgate; const float* bgate;
  float* ws; float* out;
};

// ---------------------------------------------------------------------------
// tree barrier + captain fence.
// bar layout (u32 idx): grp[g]=g*64, root=512, capcnt=576, rel[g]=640+g*64,
// capslot[8]=2048.., ncap=2176.
// ---------------------------------------------------------------------------
DEV_INLINE void gbar(unsigned* bar, int blk, bool iscap, unsigned e)
{
  __syncthreads();                          // drains vmcnt: sc1 stores at MALL
  if (threadIdx.x == 0) {
    const unsigned g = (unsigned)blk >> 5;  // 8 groups x 32 blocks
    unsigned a = __hip_atomic_fetch_add(bar + g * 64, 1u, __ATOMIC_RELAXED, __HIP_MEMORY_SCOPE_AGENT);
    if (a == e * 32u - 1u)
      __hip_atomic_fetch_add(bar + 512, 1u, __ATOMIC_RELAXED, __HIP_MEMORY_SCOPE_AGENT);
    if (iscap) {
      while (__hip_atomic_load(bar + 512, __ATOMIC_RELAXED, __HIP_MEMORY_SCOPE_AGENT) < e * 8u)
        __builtin_amdgcn_s_sleep(1);
      __builtin_amdgcn_fence(__ATOMIC_ACQUIRE, "agent");    // waitcnt + L2(+L1) inv, this XCD
      const unsigned nc = __hip_atomic_load(bar + 2176, __ATOMIC_RELAXED, __HIP_MEMORY_SCOPE_AGENT);
      unsigned c = __hip_atomic_fetch_add(bar + 576, 1u, __ATOMIC_RELAXED, __HIP_MEMORY_SCOPE_AGENT);
      if (c == e * nc - 1u) {
#pragma unroll
        for (unsigned i = 0; i < 8; ++i)
          __hip_atomic_store(bar + 640 + i * 64, e, __ATOMIC_RELAXED, __HIP_MEMORY_SCOPE_AGENT);
      }
    }
    {
      const unsigned g2 = (unsigned)blk >> 5;
      while (__hip_atomic_load(bar + 640 + g2 * 64, __ATOMIC_RELAXED, __HIP_MEMORY_SCOPE_AGENT) < e)
        __builtin_amdgcn_s_sleep(4);
    }
  }
  __syncthreads();
  asm volatile("buffer_inv sc0\n\ts_waitcnt vmcnt(0)" ::: "memory");  // local vL1 inv
}

// ---------------------------------------------------------------------------
// GEMM segment, 16 rows (4 units x 4 gates), global cached weights.
// rows[j] = u0 + (j>>2) + 512*(j&3). lane = batch. K-slice [ks,ke).
// ---------------------------------------------------------------------------
DEV_INLINE void gseg16(float* __restrict__ acc,
                       const float* __restrict__ inT,
                       const float* __restrict__ W, const int ldw, const int wcol0,
                       const int u0, const int segk0, const int seglen,
                       const int ks, const int ke, const int lane)
{
  const int a0 = ks > segk0 ? ks : segk0;
  const int a1 = (ke < segk0 + seglen) ? ke : (segk0 + seglen);
  if (a0 >= a1) return;
  const float* __restrict__ ip = inT + (size_t)(a0 - segk0) * 64 + lane;
  const int n = a1 - a0;
  const float* wp[16];
#pragma unroll
  for (int j = 0; j < 16; ++j) {
    const int row = u0 + (j >> 2) + 512 * (j & 3);
    wp[j] = W + (size_t)row * ldw + (wcol0 + (a0 - segk0));
  }
  for (int k = 0; k < n; k += 4) {
    const float x0 = ip[(k + 0) * 64];
    const float x1 = ip[(k + 1) * 64];
    const float x2 = ip[(k + 2) * 64];
    const float x3 = ip[(k + 3) * 64];
#pragma unroll
    for (int j = 0; j < 16; ++j)
      acc[j] += x0 * wp[j][k] + x1 * wp[j][k + 1] + x2 * wp[j][k + 2] + x3 * wp[j][k + 3];
  }
}

// small-N segment for mel/gate (global cached weights)
template<int NO>
DEV_INLINE void gseg(float* __restrict__ acc,
                     const float* __restrict__ inT,
                     const float* __restrict__ W, const int ldw, const int wcol0,
                     const int* __restrict__ rows, const int segk0, const int seglen,
                     const int ks, const int ke, const int lane)
{
  const int a0 = ks > segk0 ? ks : segk0;
  const int a1 = (ke < segk0 + seglen) ? ke : (segk0 + seglen);
  if (a0 >= a1) return;
  const float* __restrict__ ip = inT + (size_t)(a0 - segk0) * 64 + lane;
  const int n = a1 - a0;
  const float* wp[NO];
#pragma unroll
  for (int j = 0; j < NO; ++j)
    wp[j] = W + (size_t)rows[j] * ldw + (wcol0 + (a0 - segk0));
  for (int k = 0; k < n; k += 4) {
    const float x0 = ip[(k + 0) * 64];
    const float x1 = ip[(k + 1) * 64];
    const float x2 = ip[(k + 2) * 64];
    const float x3 = ip[(k + 3) * 64];
#pragma unroll
    for (int j = 0; j < NO; ++j)
      acc[j] += x0 * wp[j][k] + x1 * wp[j][k + 1] + x2 * wp[j][k + 2] + x3 * wp[j][k + 3];
  }
}

// ---------------------------------------------------------------------------
__global__ __launch_bounds__(256) void init_kernel(const float* __restrict__ Wq,
                                                   float* __restrict__ ws)
{
  const int i = blockIdx.x * 256 + threadIdx.x;       // 65536 threads
  {
    const int k = i >> 7, a = i & 127;                // WqT[k][a] = Wq[a][k]
    ws[WQT_O + i] = Wq[a * 512 + k];
  }
  for (size_t idx = i; idx < ZERO_N; idx += 65536)    // zero locF..states..barrier
    ws[LOCF_O + idx] = 0.0f;
}

// ---------------------------------------------------------------------------
// host-side prenet for x(0), x(1): block j handles t = j, writes ring slot j.
// ---------------------------------------------------------------------------
__global__ __launch_bounds__(256) void prenet_kernel(const float* __restrict__ mels,
                                                     const float* __restrict__ Wp1,
                                                     const float* __restrict__ Wp2,
                                                     const float* __restrict__ Wp3,
                                                     float* __restrict__ xb)
{
  __shared__ float smem[16384];
  const int t = blockIdx.x;
  const int tid = threadIdx.x;
  const int lane = tid & 63;
  const int wv = __builtin_amdgcn_readfirstlane(tid >> 6);

  if (t == 0) {
    for (int i = tid; i < 5200; i += 256) smem[i] = 0.0f;
  } else {
    for (int i = tid; i < 5120; i += 256) {
      const int b = i / 80, k = i - b * 80;
      smem[k * 65 + b] = mels[((size_t)b * TB + (t - 1)) * 80 + k];
    }
  }
  __syncthreads();

  float va[8][8];
#pragma unroll
  for (int g = 0; g < 8; ++g) {                    // L1: K=80
    const int u0 = wv * 64 + g * 8;
    float acc[8] = {};
    for (int k = 0; k < 80; ++k) {
      const float x = smem[k * 65 + lane];
#pragma unroll
      for (int j = 0; j < 8; ++j) acc[j] += x * Wp1[(u0 + j) * 80 + k];
    }
#pragma unroll
    for (int j = 0; j < 8; ++j) va[g][j] = fmaxf(acc[j], 0.0f);
  }
  __syncthreads();
#pragma unroll
  for (int g = 0; g < 8; ++g)
#pragma unroll
    for (int j = 0; j < 8; ++j) smem[(wv * 64 + g * 8 + j) * 64 + lane] = va[g][j];
  __syncthreads();

#pragma unroll
  for (int g = 0; g < 8; ++g) {                    // L2: K=256
    const int u0 = wv * 64 + g * 8;
    float acc[8] = {};
    for (int k = 0; k < 256; ++k) {
      const float x = smem[k * 64 + lane];
#pragma unroll
      for (int j = 0; j < 8; ++j) acc[j] += x * Wp2[(u0 + j) * 256 + k];
    }
#pragma unroll
    for (int j = 0; j < 8; ++j) va[g][j] = fmaxf(acc[j], 0.0f);
  }
  __syncthreads();
#pragma unroll
  for (int g = 0; g < 8; ++g)
#pragma unroll
    for (int j = 0; j < 8; ++j) smem[(wv * 64 + g * 8 + j) * 64 + lane] = va[g][j];
  __syncthreads();

#pragma unroll
  for (int g = 0; g < 8; ++g) {                    // L3: K=256 -> ring slot
    const int u0 = wv * 64 + g * 8;
    float acc[8] = {};
    for (int k = 0; k < 256; ++k) {
      const float x = smem[k * 64 + lane];
#pragma unroll
      for (int j = 0; j < 8; ++j) acc[j] += x * Wp3[(u0 + j) * 256 + k];
    }
#pragma unroll
    for (int j = 0; j < 8; ++j)
      xb[((size_t)t * 256 + (u0 + j)) * 64 + lane] = fmaxf(acc[j], 0.0f);
  }
}

// ---------------------------------------------------------------------------
// processed_memory: pmT[b][a][l] = sum_k enc[b,l,k]*Wm[a,k]. 256 blocks.
// ---------------------------------------------------------------------------
__global__ __launch_bounds__(256) void pm_kernel(const float* __restrict__ enc,
                                                 const float* __restrict__ Wm,
                                                 float* __restrict__ pmT)
{
  __shared__ float encL[64 * 129];
  const int b = blockIdx.x >> 2;
  const int l0 = (blockIdx.x & 3) * 64;
  const int tid = threadIdx.x;
  const int lane = tid & 63;
  const int wv = __builtin_amdgcn_readfirstlane(tid >> 6);

  float acc[4][8];
#pragma unroll
  for (int ai = 0; ai < 4; ++ai)
#pragma unroll
    for (int j = 0; j < 8; ++j) acc[ai][j] = 0.0f;

  for (int kc = 0; kc < 4; ++kc) {
    __syncthreads();
    for (int i = tid; i < 64 * 128; i += 256) {
      const int l = i >> 7, k = i & 127;
      encL[l * 129 + k] = enc[((size_t)b * 256 + l0 + l) * 512 + kc * 128 + k];
    }
    __syncthreads();
#pragma unroll
    for (int ai = 0; ai < 4; ++ai) {
      const int agrp = (ai * 4 + wv) * 8;
      for (int k = 0; k < 128; ++k) {
        const float x = encL[lane * 129 + k];
#pragma unroll
        for (int j = 0; j < 8; ++j)
          acc[ai][j] += x * Wm[(size_t)(agrp + j) * 512 + kc * 128 + k];
      }
    }
  }
#pragma unroll
  for (int ai = 0; ai < 4; ++ai) {
    const int agrp = (ai * 4 + wv) * 8;
#pragma unroll
    for (int j = 0; j < 8; ++j)
      pmT[((size_t)b * 128 + agrp + j) * 256 + l0 + lane] = acc[ai][j];
  }
}

// ------------------------- persistent-kernel roles -------------------------

DEV_INLINE void f_dgates4(int u0, int tid, int lane, int wv,
                          const float* __restrict__ ah, const float* __restrict__ dh,
                          float* __restrict__ gdL, const Params& p, float* sm)
{
  float acc[16] = {};
  const int ks = wv * 256, ke = ks + 256;           // K = 1024 (ah | dh)
  gseg16(acc, ah, p.dWih, 1024, 0, u0, 0,   512, ks, ke, lane);
  gseg16(acc, dh, p.dWhh, 512,  0, u0, 512, 512, ks, ke, lane);
#pragma unroll
  for (int j = 0; j < 16; ++j) sm[(wv * 16 + j) * 64 + lane] = acc[j];
  __syncthreads();
  {
    const int m = tid & 63, uq = tid >> 6;
    const int u = u0 + uq;
#pragma unroll
    for (int q = 0; q < 4; ++q) {
      const int j = uq * 4 + q;
      gdL[j * 64 + m] = sm[j * 64 + m] + sm[(16 + j) * 64 + m] + sm[(32 + j) * 64 + m] + sm[(48 + j) * 64 + m]
                      + p.dbih[u + 512 * q] + p.dbhh[u + 512 * q];
    }
  }
  __syncthreads();
}

DEV_INLINE void f_dfin4(int u0, int tid, int lane, int wv,
                        const float* __restrict__ ctx, const float* __restrict__ gdL,
                        float* __restrict__ dh_o, float* __restrict__ dhL, float* __restrict__ dcL,
                        const Params& p, float* sm)
{
  float acc[16] = {};
  const int ks = wv * 128, ke = ks + 128;           // K = 512 (ctx)
  gseg16(acc, ctx, p.dWih, 1024, 512, u0, 0, 512, ks, ke, lane);
#pragma unroll
  for (int j = 0; j < 16; ++j) sm[(wv * 16 + j) * 64 + lane] = acc[j];
  __syncthreads();
  {
    const int m = tid & 63, uq = tid >> 6;
    const int u = u0 + uq;
    float g[4];
#pragma unroll
    for (int q = 0; q < 4; ++q) {
      const int j = uq * 4 + q;
      g[q] = sm[j * 64 + m] + sm[(16 + j) * 64 + m] + sm[(32 + j) * 64 + m] + sm[(48 + j) * 64 + m]
           + gdL[j * 64 + m];
    }
    const float ho = dhL[uq * 64 + m], co = dcL[uq * 64 + m];
    const float c2 = sigf(g[1]) * co + sigf(g[0]) * tanhfast(g[2]);
    const float h2 = sigf(g[3]) * tanhfast(c2);
    const float hn = 0.1f * ho + 0.9f * h2;
    const float cn = 0.1f * co + 0.9f * c2;
    stc(dh_o + (size_t)u * 64 + m, hn);
    dhL[uq * 64 + m] = hn;
    dcL[uq * 64 + m] = cn;
  }
  __syncthreads();
}

DEV_INLINE void f_alstm4(int u0, int tid, int lane, int wv,
                         const float* __restrict__ xt, const float* __restrict__ ctx,
                         const float* __restrict__ ahg,
                         float* __restrict__ ah_o, float* __restrict__ ahL, float* __restrict__ acL,
                         const Params& p, float* sm)
{
  float acc[16] = {};
  const int ks = wv * 320, ke = ks + 320;           // K = 256+512+512
  gseg16(acc, xt,  p.aWih, 768, 0,   u0, 0,   256, ks, ke, lane);
  gseg16(acc, ctx, p.aWih, 768, 256, u0, 256, 512, ks, ke, lane);
  gseg16(acc, ahg, p.aWhh, 512, 0,   u0, 768, 512, ks, ke, lane);
#pragma unroll
  for (int j = 0; j < 16; ++j) sm[(wv * 16 + j) * 64 + lane] = acc[j];
  __syncthreads();
  {
    const int m = tid & 63, uq = tid >> 6;
    const int u = u0 + uq;
    float g[4];
#pragma unroll
    for (int q = 0; q < 4; ++q) {
      const int j = uq * 4 + q;
      g[q] = sm[j * 64 + m] + sm[(16 + j) * 64 + m] + sm[(32 + j) * 64 + m] + sm[(48 + j) * 64 + m]
           + p.abih[u + 512 * q] + p.abhh[u + 512 * q];
    }
    const float ho = ahL[uq * 64 + m], co = acL[uq * 64 + m];
    const float c2 = sigf(g[1]) * co + sigf(g[0]) * tanhfast(g[2]);
    const float h2 = sigf(g[3]) * tanhfast(c2);
    const float hn = 0.1f * ho + 0.9f * h2;
    const float cn = 0.1f * co + 0.9f * c2;
    stc(ah_o + (size_t)u * 64 + m, hn);
    ahL[uq * 64 + m] = hn;
    acL[uq * 64 + m] = cn;
  }
  __syncthreads();
}

DEV_INLINE void f_mel(int c0, int tid, int lane, int wv, int tm1,
                      const float* __restrict__ dh, const float* __restrict__ ctx,
                      const Params& p, float* sm)
{
  int rows[4] = {c0, c0 + 1, c0 + 2, c0 + 3};
  float acc[4] = {};
  const int ks = wv * 256, ke = ks + 256;           // K = 1024
  gseg<4>(acc, dh,  p.Wout, 1024, 0,   rows, 0,   512, ks, ke, lane);
  gseg<4>(acc, ctx, p.Wout, 1024, 512, rows, 512, 512, ks, ke, lane);
#pragma unroll
  for (int j = 0; j < 4; ++j) sm[(wv * 4 + j) * 64 + lane] = acc[j];
  __syncthreads();
  {
    const int m = tid & 63, c = tid >> 6;
    const float val = sm[c * 64 + m] + sm[(4 + c) * 64 + m] + sm[(8 + c) * 64 + m] + sm[(12 + c) * 64 + m]
                    + p.bout[c0 + c];
    stc(p.out + MEL_O + ((size_t)m * TB + tm1) * 80 + c0 + c, val);
  }
  __syncthreads();
}

DEV_INLINE void f_gate(int tid, int lane, int wv, int tm1,
                       const float* __restrict__ dh, const float* __restrict__ ctx,
                       const Params& p, float* sm)
{
  float acc[1] = {};
  int rows1[1] = {0};
  const int ks = wv * 256, ke = ks + 256;
  gseg<1>(acc, dh,  p.Wgate, 1024, 0,   rows1, 0,   512, ks, ke, lane);
  gseg<1>(acc, ctx, p.Wgate, 1024, 512, rows1, 512, 512, ks, ke, lane);
  sm[wv * 64 + lane] = acc[0];
  __syncthreads();
  if (tid < 64) {
    const float val = sm[tid] + sm[64 + tid] + sm[128 + tid] + sm[192 + tid] + p.bgate[0];
    stc(p.out + GATE_O + (size_t)tid * TB + tm1, val);
  }
  __syncthreads();
}

DEV_INLINE void f_conv(int b, int tid,
                       const float* __restrict__ aw, const float* __restrict__ aws,
                       float* __restrict__ locF, const Params& p, float* sm)
{
  float* awL  = sm;          // 286 (+pad)
  float* awsL = sm + 290;
  if (tid < 15) { awL[tid] = 0.0f; awsL[tid] = 0.0f; awL[271 + tid] = 0.0f; awsL[271 + tid] = 0.0f; }
  awL[15 + tid]  = aw[b * 256 + tid];
  awsL[15 + tid] = aws[b * 256 + tid];
  __syncthreads();
  float awv[31], awsv[31];
#pragma unroll
  for (int k = 0; k < 31; ++k) { awv[k] = awL[tid + k]; awsv[k] = awsL[tid + k]; }
  float* dst = locF + ((size_t)b * 256 + tid) * 32;
  for (int f = 0; f < 32; ++f) {
    const float* wc = p.Wconv + f * 62;
    float lf = 0.0f;
#pragma unroll
    for (int k = 0; k < 31; ++k) lf += awv[k] * wc[k] + awsv[k] * wc[31 + k];
    stc(dst + f, lf);
  }
  __syncthreads();
}

DEV_INLINE void f_energy(int b, int t, int tid, int lane, int wv,
                         const float* __restrict__ ah, const float* __restrict__ aws_p,
                         float* __restrict__ ctx_o, float* __restrict__ aw_o,
                         float* __restrict__ aws_o,
                         const float* __restrict__ pmT, const float* __restrict__ wqT,
                         const float* __restrict__ locF, const Params& p, float* sm)
{
  float* ahL = sm;          // 512
  float* qpL = sm + 512;    // 256
  float* qL  = sm + 768;    // 128
  float* red = sm + 896;    // 16
  float* wL  = sm + 912;    // 256
  ahL[tid]       = ah[(size_t)tid * 64 + b];
  ahL[tid + 256] = ah[(size_t)(tid + 256) * 64 + b];
  __syncthreads();
  {
    const int a = tid & 127, h = tid >> 7;
    float qp = 0.0f;
    const float* wq = wqT + (size_t)(h * 256) * 128 + a;
    const float* xv = ahL + h * 256;
    for (int k = 0; k < 256; k += 4)
      qp += wq[(k + 0) * 128] * xv[k + 0] + wq[(k + 1) * 128] * xv[k + 1]
          + wq[(k + 2) * 128] * xv[k + 2] + wq[(k + 3) * 128] * xv[k + 3];
    qpL[tid] = qp;
  }
  __syncthreads();
  if (tid < 128) qL[tid] = qpL[tid] + qpL[128 + tid];
  __syncthreads();

  float locv[32];
  {
    const float4* lf4 = (const float4*)(locF + ((size_t)b * 256 + tid) * 32);
#pragma unroll
    for (int i = 0; i < 8; ++i) {
      float4 x = lf4[i];
      locv[4*i] = x.x; locv[4*i+1] = x.y; locv[4*i+2] = x.z; locv[4*i+3] = x.w;
    }
  }
  float part = 0.0f;
  const float* pmp = pmT + (size_t)b * 32768 + tid;     // pm[b][a][l=tid]
#pragma unroll 2
  for (int a = 0; a < 128; ++a) {
    float s = qL[a] + pmp[(size_t)a * 256];
    const float* wl = p.Wloc + a * 32;
#pragma unroll
    for (int f = 0; f < 32; ++f) s += locv[f] * wl[f];
    part += p.v[a] * tanhfast(s);
  }
  if (tid >= p.len[b]) part = -1e9f;

  float mv = part;
  for (int mm = 32; mm >= 1; mm >>= 1) mv = fmaxf(mv, __shfl_xor(mv, mm, 64));
  if (lane == 0) red[wv] = mv;
  __syncthreads();
  const float mx = fmaxf(fmaxf(red[0], red[1]), fmaxf(red[2], red[3]));
  const float pex = __expf(part - mx);
  float ssum = pex;
  for (int mm = 32; mm >= 1; mm >>= 1) ssum += __shfl_xor(ssum, mm, 64);
  if (lane == 0) red[8 + wv] = ssum;
  __syncthreads();
  const float inv = 1.0f / (red[8] + red[9] + red[10] + red[11]);
  const float w = pex * inv;
  wL[tid] = w;
  stc(aw_o + b * 256 + tid, w);
  stc(aws_o + b * 256 + tid, aws_p[b * 256 + tid] + w);
  stc(p.out + ALG_O + ((size_t)b * TB + t) * 256 + tid, w);
  __syncthreads();

  float c0 = 0.0f, c1 = 0.0f;
  const float* ep = p.enc + (size_t)b * 256 * 512;
  for (int l = 0; l < 256; ++l) {
    const float wv_ = wL[l];
    c0 += wv_ * ep[(size_t)l * 512 + tid];
    c1 += wv_ * ep[(size_t)l * 512 + tid + 256];
  }
  stc(ctx_o + (size_t)tid * 64 + b, c0);
  stc(ctx_o + (size_t)(tid + 256) * 64 + b, c1);
  __syncthreads();
}

// prenet L1: 8 blocks x 32 u; reads mels[:, frame]
DEV_INLINE void f_pn1(int blkL, int frame, int lane, int wv,
                      const Params& p, float* __restrict__ y1)
{
  const int u0 = blkL * 32 + wv * 8;
  float acc[8] = {};
  const float* mp = p.mels + ((size_t)lane * TB + frame) * 80;
  for (int k = 0; k < 80; ++k) {
    const float x = mp[k];
#pragma unroll
    for (int j = 0; j < 8; ++j) acc[j] += x * p.Wp1[(u0 + j) * 80 + k];
  }
#pragma unroll
  for (int j = 0; j < 8; ++j) stc(y1 + (size_t)(u0 + j) * 64 + lane, fmaxf(acc[j], 0.0f));
}

// prenet mid layer (L2 or L3): yin [256][64] -> yout [256][64]
DEV_INLINE void f_pnmid(int blkL, int lane, int wv,
                        const float* __restrict__ yin, const float* __restrict__ W,
                        float* __restrict__ yout)
{
  const int u0 = blkL * 32 + wv * 8;
  float acc[8] = {};
  for (int k = 0; k < 256; ++k) {
    const float x = yin[(size_t)k * 64 + lane];
#pragma unroll
    for (int j = 0; j < 8; ++j) acc[j] += x * W[(u0 + j) * 256 + k];
  }
#pragma unroll
  for (int j = 0; j < 8; ++j) stc(yout + (size_t)(u0 + j) * 64 + lane, fmaxf(acc[j], 0.0f));
}

// ---------------------------------------------------------------------------
__global__ __launch_bounds__(256) void persist_kernel(Params p)
{
  __shared__ float sm[4096];
  __shared__ float gdL[1024];
  __shared__ float s1L[256];    // X: dhL (own) ; Y: ahL (own)
  __shared__ float s2L[256];    // X: dcL       ; Y: acL
  __shared__ unsigned capflag;

  const int tid = threadIdx.x, blk = blockIdx.x;
  const int lane = tid & 63;
  const int wv = __builtin_amdgcn_readfirstlane(tid >> 6);
  const bool isX = blk < 128;
  const int yi = blk - 128;

  float* ws   = p.ws;
  float* pmT  = ws + PMT_O;
  float* wqT  = ws + WQT_O;
  float* locF = ws + LOCF_O;
  float* y1   = ws + Y1_O;
  float* y2   = ws + Y2_O;
  float* xr   = ws + XR_O;
  float* AH[2]  = {ws + AH_O,  ws + AH_O  + 32768};
  float* DH[2]  = {ws + DH_O,  ws + DH_O  + 32768};
  float* CTX[2] = {ws + CTX_O, ws + CTX_O + 32768};
  float* AW[2]  = {ws + AW_O,  ws + AW_O  + 16384};
  float* AWS[2] = {ws + AWS_O, ws + AWS_O + 16384};
  unsigned* bar = (unsigned*)(ws + BAR_O);

  // zero block-private state; elect one captain per XCD
  s1L[tid] = 0.0f; s2L[tid] = 0.0f;
  if (tid == 0) {
    unsigned x;
    asm volatile("s_getreg_b32 %0, hwreg(HW_REG_XCC_ID)" : "=s"(x));
    unsigned prev = __hip_atomic_fetch_add(bar + 2048 + (x & 7), 1u,
                                           __ATOMIC_RELAXED, __HIP_MEMORY_SCOPE_AGENT);
    if (prev == 0)
      __hip_atomic_fetch_add(bar + 2176, 1u, __ATOMIC_RELAXED, __HIP_MEMORY_SCOPE_AGENT);
    capflag = (prev == 0) ? 1u : 0u;
  }
  __syncthreads();
  const bool iscap = (capflag != 0);
  unsigned e = 0;

  // S0: prenet L1 for x(2) (frame = mels[:,1])
  if (!isX && yi >= 85 && yi < 93) f_pn1(yi - 85, 1, lane, wv, p, y1);
  gbar(bar, blk, iscap, ++e);

  // S1: aLSTM(0) from zero state (Y) || pn L2(x(2)) (X 0-7). locF(0)=0.
  if (!isX) {
    f_alstm4(yi * 4, tid, lane, wv, xr, CTX[1], AH[1], AH[0], s1L, s2L, p, sm);
  } else if (blk < 8) {
    f_pnmid(blk, lane, wv, y1, p.Wp2, y2);
  }
  gbar(bar, blk, iscap, ++e);

  for (int t = 0; t < TB; ++t) {
    const int cur = t & 1, prv = cur ^ 1;
    // ---- p2(t) ----
    if (isX) {
      f_dgates4(blk * 4, tid, lane, wv, AH[cur], DH[prv], gdL, p, sm);
    } else if (yi < 64) {
      f_energy(yi, t, tid, lane, wv, AH[cur], AWS[prv],
               CTX[cur], AW[cur], AWS[cur], pmT, wqT, locF, p, sm);
    } else if (yi < 84) {
      if (t > 0) f_mel((yi - 64) * 4, tid, lane, wv, t - 1, DH[prv], CTX[prv], p, sm);
    } else if (yi == 84) {
      if (t > 0) f_gate(tid, lane, wv, t - 1, DH[prv], CTX[prv], p, sm);
    } else if (yi < 93) {
      if (t <= 796) f_pn1(yi - 85, t + 2, lane, wv, p, y1);          // L1 for x(t+3)
    } else if (yi < 101) {
      if (t <= 797) f_pnmid(yi - 93, lane, wv, y2, p.Wp3, xr + (size_t)cur * 16384); // L3 -> x(t+2)
    }
    gbar(bar, blk, iscap, ++e);

    // ---- p1(t) ----
    if (isX) {
      f_dfin4(blk * 4, tid, lane, wv, CTX[cur], gdL, DH[cur], s1L, s2L, p, sm);
      if (blk >= 64) {
        if (t < TB - 1) f_conv(blk - 64, tid, AW[cur], AWS[cur], locF, p, sm);   // locF(t+1)
      } else if (blk < 8) {
        if (t <= 796) f_pnmid(blk, lane, wv, y1, p.Wp2, y2);         // L2 for x(t+3)
      }
    } else {
      if (t < TB - 1)
        f_alstm4(yi * 4, tid, lane, wv, xr + (size_t)prv * 16384, CTX[cur],
                 AH[cur], AH[prv], s1L, s2L, p, sm);
    }
    gbar(bar, blk, iscap, ++e);
  }
  // final mel/gate for t = 799 (dh,ctx in buf[1])
  if (!isX) {
    if (yi >= 64 && yi < 84)  f_mel((yi - 64) * 4, tid, lane, wv, TB - 1, DH[1], CTX[1], p, sm);
    else if (yi == 84)        f_gate(tid, lane, wv, TB - 1, DH[1], CTX[1], p, sm);
  }
}

// ---------------------------------------------------------------------------
extern "C" void kernel_launch(void* const* d_in, const int* in_sizes, int n_in,
                              void* d_out, int out_size, void* d_ws, size_t ws_size,
                              hipStream_t stream)
{
  (void)in_sizes; (void)n_in; (void)out_size; (void)ws_size;
  Params P;
  P.enc   = (const float*)d_in[0];
  P.len   = (const int*)  d_in[1];
  P.mels  = (const float*)d_in[2];
  P.Wp1   = (const float*)d_in[3];
  P.Wp2   = (const float*)d_in[4];
  P.Wp3   = (const float*)d_in[5];
  P.aWih  = (const float*)d_in[6];
  P.aWhh  = (const float*)d_in[7];
  P.abih  = (const float*)d_in[8];
  P.abhh  = (const float*)d_in[9];
  P.dWih  = (const float*)d_in[10];
  P.dWhh  = (const float*)d_in[11];
  P.dbih  = (const float*)d_in[12];
  P.dbhh  = (const float*)d_in[13];
  const float* Wq = (const float*)d_in[14];
  const float* Wm = (const float*)d_in[15];
  P.Wconv = (const float*)d_in[16];
  P.Wloc  = (const float*)d_in[17];
  P.v     = (const float*)d_in[18];
  P.Wout  = (const float*)d_in[19];
  P.bout  = (const float*)d_in[20];
  P.Wgate = (const float*)d_in[21];
  P.bgate = (const float*)d_in[22];
  P.ws  = (float*)d_ws;
  P.out = (float*)d_out;

  init_kernel<<<256, 256, 0, stream>>>(Wq, P.ws);
  pm_kernel<<<256, 256, 0, stream>>>(P.enc, Wm, P.ws + PMT_O);
  prenet_kernel<<<2, 256, 0, stream>>>(P.mels, P.Wp1, P.Wp2, P.Wp3, P.ws + XR_O);

  persist_kernel<<<256, 256, 0, stream>>>(P);
}